// Round 8
// baseline (107.513 us; speedup 1.0000x reference)
//
#include <hip/hip_runtime.h>
#include <hip/hip_bf16.h>
#include <math.h>

#define QSCALE 0.125f

typedef __attribute__((ext_vector_type(8))) short short8b;   // 8 bf16 (4 VGPRs)
typedef __attribute__((ext_vector_type(8))) _Float16 half8;  // 8 f16  (4 VGPRs)
typedef __attribute__((ext_vector_type(4))) float f32x4;

// HW packed f32->bf16 (RNE): 1 instr per pair. No builtin on gfx950 (T12).
__device__ __forceinline__ uint pack2(float a, float b) {
    uint r;
    asm("v_cvt_pk_bf16_f32 %0, %1, %2" : "=v"(r) : "v"(a), "v"(b));
    return r;
}
// packed f32->2xf16 (RTZ), single instr
__device__ __forceinline__ uint pkrtz(float a, float b) {
    uint r;
    asm("v_cvt_pkrtz_f16_f32 %0, %1, %2" : "=v"(r) : "v"(a), "v"(b));
    return r;
}
__device__ __forceinline__ uint pk_fma_f16(uint a, uint b, uint c) {
    uint r;
    asm("v_pk_fma_f16 %0, %1, %2, %3" : "=v"(r) : "v"(a), "v"(b), "v"(c));
    return r;
}
__device__ __forceinline__ uint pk_max_f16(uint a, uint b) {
    uint r;
    asm("v_pk_max_f16 %0, %1, %2" : "=v"(r) : "v"(a), "v"(b));
    return r;
}
__device__ __forceinline__ float slogf_(float p) {
    return copysignf(log1pf(fabsf(p)), p);
}

// ---------------- q projection: per (b,g) 64x64 @ 64x1024 ----------------
__global__ __launch_bounds__(256) void k_qproj(const float* __restrict__ x,
                                               const float* __restrict__ wq,
                                               float* __restrict__ q,
                                               short* __restrict__ qbt) {
    __shared__ float Wst[64 * 64];   // [ci][co]
    __shared__ float xs[64 * 128];   // [ci][hw]
    int ht = blockIdx.x, g = blockIdx.y, b = blockIdx.z;
    int tid = threadIdx.x;
    for (int e = tid; e < 4096; e += 256) {
        int co = e >> 6, ci = e & 63;
        Wst[ci * 64 + co] = wq[(g * 64 + co) * 64 + ci];
    }
    const float* xb = x + (b * 256 + g * 64) * 1024 + ht * 128;
    for (int e = tid; e < 2048; e += 256) {
        int ci = e >> 5, hq = e & 31;
        *(float4*)&xs[ci * 128 + hq * 4] = *(const float4*)&xb[ci * 1024 + hq * 4];
    }
    __syncthreads();
    int cg = tid >> 4, hg = tid & 15;
    int co0 = cg * 4, hw0 = hg * 8;
    float acc[4][8];
    for (int a = 0; a < 4; a++) for (int c = 0; c < 8; c++) acc[a][c] = 0.f;
    for (int ci = 0; ci < 64; ci++) {
        float4 a4 = *(float4*)&Wst[ci * 64 + co0];
        float4 b0 = *(float4*)&xs[ci * 128 + hw0];
        float4 b1 = *(float4*)&xs[ci * 128 + hw0 + 4];
        float av[4] = {a4.x, a4.y, a4.z, a4.w};
        float bv[8] = {b0.x, b0.y, b0.z, b0.w, b1.x, b1.y, b1.z, b1.w};
        #pragma unroll
        for (int a = 0; a < 4; a++)
            #pragma unroll
            for (int c = 0; c < 8; c++) acc[a][c] += av[a] * bv[c];
    }
    float* qb = q + (b * 256 + g * 64) * 1024 + ht * 128;
    for (int a = 0; a < 4; a++) {
        float4 o0 = {acc[a][0], acc[a][1], acc[a][2], acc[a][3]};
        float4 o1 = {acc[a][4], acc[a][5], acc[a][6], acc[a][7]};
        *(float4*)&qb[(co0 + a) * 1024 + hw0] = o0;
        *(float4*)&qb[(co0 + a) * 1024 + hw0 + 4] = o1;
    }
    short* q16 = qbt + ((size_t)((b * 4 + g) * 1024 + ht * 128)) * 64;
    for (int c = 0; c < 8; c++) {
        int i = hw0 + c;
        uint2 uu;
        uu.x = pack2(acc[0][c] * QSCALE, acc[1][c] * QSCALE);
        uu.y = pack2(acc[2][c] * QSCALE, acc[3][c] * QSCALE);
        *(uint2*)&q16[i * 64 + co0] = uu;
    }
}

// --------- offsets stage 1: depthwise conv6x6 s4 p1 + GELU ---------------
__global__ __launch_bounds__(256) void k_dw(const float* __restrict__ q,
                                            const float* __restrict__ wdw,
                                            const float* __restrict__ bdw,
                                            float* __restrict__ gdw) {
    __shared__ float qs[8 * 1024];
    __shared__ float wds[8 * 36];
    int cg = blockIdx.x, n = blockIdx.y;
    int b = n >> 2, gg = n & 3;
    int c0 = cg * 8;
    int tid = threadIdx.x;
    const float* qn = q + (b * 256 + gg * 64 + c0) * 1024;
    for (int e = tid; e < 2048; e += 256)
        ((float4*)qs)[e] = ((const float4*)qn)[e];
    for (int e = tid; e < 288; e += 256)
        wds[e] = wdw[c0 * 36 + e];
    __syncthreads();
    for (int e = tid; e < 512; e += 256) {
        int c = e >> 6, pos = e & 63;
        int oy = pos >> 3, ox = pos & 7;
        float acc = bdw[c0 + c];
        #pragma unroll
        for (int ky = 0; ky < 6; ky++) {
            int iy = oy * 4 - 1 + ky;
            if (iy < 0 || iy > 31) continue;
            #pragma unroll
            for (int kx = 0; kx < 6; kx++) {
                int ix = ox * 4 - 1 + kx;
                if (ix < 0 || ix > 31) continue;
                acc += qs[c * 1024 + iy * 32 + ix] * wds[c * 36 + ky * 6 + kx];
            }
        }
        gdw[(n * 64 + c0 + c) * 64 + pos] = acc * 0.5f * (1.f + erff(acc * 0.70710678118654752f));
    }
}

// --------- offsets stage 2: 1x1 conv + tanh*4 -> normalized grid ----------
__global__ __launch_bounds__(64) void k_pw(const float* __restrict__ gdw,
                                           const float* __restrict__ wpw,
                                           float* __restrict__ vgs) {
    int n = blockIdx.x, pos = threadIdx.x;
    const float* gp = gdw + n * 4096 + pos;
    float a0 = 0.f, a1 = 0.f;
    #pragma unroll 8
    for (int c = 0; c < 64; c++) {
        float v = gp[c * 64];
        a0 += v * wpw[c];
        a1 += v * wpw[64 + c];
    }
    float offx = tanhf(a0) * 4.0f, offy = tanhf(a1) * 4.0f;
    int oy = pos >> 3, ox = pos & 7;
    vgs[(n * 64 + pos) * 2]     = 2.f * ((float)ox + offx) / 7.f - 1.f;
    vgs[(n * 64 + pos) * 2 + 1] = 2.f * ((float)oy + offy) / 7.f - 1.f;
}

// ---- u0 table precompute: u0g[n][ix][j] = pk(slog(qx(ix)-kx[n,j])) -------
__global__ __launch_bounds__(256) void k_u0(const float* __restrict__ vgs,
                                            uint* __restrict__ u0g) {
    int n = blockIdx.x, tid = threadIdx.x;
    for (int e = tid; e < 2048; e += 256) {
        int ix = e >> 6, j = e & 63;
        float qx = (2.f / 31.f) * (float)ix - 1.f;
        float u = slogf_(qx - vgs[(n << 7) + j * 2]);
        u0g[n * 2048 + e] = pkrtz(u, u);
    }
}

// ------------- grid_sample (bilinear, zeros, align_corners=F) -------------
__global__ __launch_bounds__(256) void k_sample(const float* __restrict__ x,
                                                const float* __restrict__ vgs,
                                                float* __restrict__ kv) {
    int idx = blockIdx.x * 256 + threadIdx.x;
    int pos = idx & 63, c = (idx >> 6) & 63, n = idx >> 12;
    int b = n >> 2, g = n & 3;
    float gx = vgs[(n * 64 + pos) * 2];
    float gy = vgs[(n * 64 + pos) * 2 + 1];
    float ix = (gx + 1.f) * 16.f - 0.5f;
    float iy = (gy + 1.f) * 16.f - 0.5f;
    float x0 = floorf(ix), y0 = floorf(iy);
    float wa = (x0 + 1.f - ix) * (y0 + 1.f - iy);
    float wb = (ix - x0) * (y0 + 1.f - iy);
    float wc = (x0 + 1.f - ix) * (iy - y0);
    float wd = (ix - x0) * (iy - y0);
    const float* img = x + (b * 256 + g * 64 + c) * 1024;
    int xi = (int)x0, yi = (int)y0;
    float acc = 0.f;
    if (xi >= 0 && xi <= 31 && yi >= 0 && yi <= 31)         acc += img[yi * 32 + xi] * wa;
    if (xi + 1 >= 0 && xi + 1 <= 31 && yi >= 0 && yi <= 31) acc += img[yi * 32 + xi + 1] * wb;
    if (xi >= 0 && xi <= 31 && yi + 1 >= 0 && yi + 1 <= 31) acc += img[(yi + 1) * 32 + xi] * wc;
    if (xi + 1 >= 0 && xi + 1 <= 31 && yi + 1 >= 0 && yi + 1 <= 31) acc += img[(yi + 1) * 32 + xi + 1] * wd;
    kv[(n * 64 + c) * 64 + pos] = acc;
}

// -------- k,v projection: per (b,g) two 64x64 @ 64x64 -> bf16 out ---------
__global__ __launch_bounds__(256) void k_kvproj(const float* __restrict__ kv,
                                                const float* __restrict__ wk,
                                                const float* __restrict__ wv,
                                                short* __restrict__ kob,
                                                short* __restrict__ vob) {
    __shared__ float kvs[4096];
    __shared__ float wkt[4096];
    __shared__ float wvt[4096];
    int n = blockIdx.x, g = n & 3;
    int tid = threadIdx.x;
    for (int e = tid; e < 4096; e += 256) {
        int co = e >> 6, ci = e & 63;
        wkt[ci * 64 + co] = wk[(g * 64 + co) * 64 + ci];
        wvt[ci * 64 + co] = wv[(g * 64 + co) * 64 + ci];
        kvs[e] = kv[n * 4096 + e];
    }
    __syncthreads();
    int cg = tid >> 4, jg = tid & 15;
    int co0 = cg * 4, j0 = jg * 4;
    float ak[4][4] = {}, av[4][4] = {};
    for (int ci = 0; ci < 64; ci++) {
        float4 a1 = *(float4*)&wkt[ci * 64 + co0];
        float4 a2 = *(float4*)&wvt[ci * 64 + co0];
        float4 b4 = *(float4*)&kvs[ci * 64 + j0];
        float w1v[4] = {a1.x, a1.y, a1.z, a1.w};
        float w2v[4] = {a2.x, a2.y, a2.z, a2.w};
        float bb[4] = {b4.x, b4.y, b4.z, b4.w};
        #pragma unroll
        for (int a = 0; a < 4; a++)
            #pragma unroll
            for (int j = 0; j < 4; j++) { ak[a][j] += w1v[a] * bb[j]; av[a][j] += w2v[a] * bb[j]; }
    }
    for (int jj = 0; jj < 4; jj++) {
        uint2 uu;
        uu.x = pack2(ak[0][jj], ak[1][jj]);
        uu.y = pack2(ak[2][jj], ak[3][jj]);
        *(uint2*)&kob[n * 4096 + (j0 + jj) * 64 + co0] = uu;
    }
    for (int a = 0; a < 4; a++) {
        uint2 uu;
        uu.x = pack2(av[a][0], av[a][1]);
        uu.y = pack2(av[a][2], av[a][3]);
        *(uint2*)&vob[n * 4096 + (co0 + a) * 64 + j0] = uu;
    }
}

// ----------- wout f32 -> bf16 pre-convert (for MFMA outproj) --------------
__global__ __launch_bounds__(256) void k_wcvt(const float* __restrict__ w,
                                              short* __restrict__ wb) {
    int e = (blockIdx.x * 256 + threadIdx.x) * 8;
    float4 f0 = *(const float4*)&w[e];
    float4 f1 = *(const float4*)&w[e + 4];
    uint4 u = {pack2(f0.x, f0.y), pack2(f0.z, f0.w), pack2(f1.x, f1.y), pack2(f1.z, f1.w)};
    *(uint4*)&wb[e] = u;
}

// ------------------- CPB bias MLP (2->64->64->1) via f16 MFMA -------------
// Grid (64 = iy*2 + xhalf, 32 n), 16 ix per block -> ~14KB LDS, 8 blocks/CU.
// u0 table from global (precomputed), Q1 built in-block (needs iy),
// b2 folded into first MFMA's C operand (no acc-init movs).
__global__ __launch_bounds__(256) void k_cpb(const float* __restrict__ vgs,
                                             const uint* __restrict__ u0g,
                                             const float* __restrict__ w1,
                                             const float* __restrict__ b1,
                                             const float* __restrict__ w2,
                                             const float* __restrict__ b2,
                                             const float* __restrict__ w3,
                                             const float* __restrict__ b3,
                                             float* __restrict__ bias) {
    __shared__ uint Q1p[64 * 36];    // [j][k-pair] f16x2, stride 36 (16B-aligned rows)
    __shared__ uint u0p[16 * 64];    // [ixl][j] f16x2
    __shared__ float u1t[64];
    int iy = blockIdx.x >> 1, xh = blockIdx.x & 1, n = blockIdx.y, tid = threadIdx.x;
    float qy = 2.f * (float)iy / 31.f - 1.f;

    if (tid < 64) u1t[tid] = slogf_(qy - vgs[(n << 7) + tid * 2 + 1]);
    __syncthreads();
    for (int e = tid; e < 2048; e += 256) {
        int j = e >> 5, pp = e & 31;
        int k = pp * 2;
        float lo = fmaf(w1[2 * k + 1], u1t[j], b1[k]);
        float hi = fmaf(w1[2 * k + 3], u1t[j], b1[k + 1]);
        Q1p[j * 36 + pp] = pkrtz(lo, hi);
    }
    for (int e = tid; e < 1024; e += 256)
        u0p[e] = u0g[n * 2048 + xh * 1024 + e];

    int wid = tid >> 6, lane = tid & 63, lr = lane & 15, g = lane >> 4;
    float b3v = b3[0];

    // A = W2 f16 fragments (constant): row c2 = m*16+lr, k = s*32+g*8+t
    half8 w2f[4][2];
    #pragma unroll
    for (int m = 0; m < 4; m++)
        #pragma unroll
        for (int s = 0; s < 2; s++) {
            const float* wp = w2 + (m * 16 + lr) * 64 + s * 32 + g * 8;
            float4 c0 = *(const float4*)wp;
            float4 c1 = *(const float4*)(wp + 4);
            uint4 uu = {pkrtz(c0.x, c0.y), pkrtz(c0.z, c0.w),
                        pkrtz(c1.x, c1.y), pkrtz(c1.z, c1.w)};
            w2f[m][s] = __builtin_bit_cast(half8, uu);
        }
    // layer-1 'a' weight pairs (f16x2) for this lane's k-slice
    uint w1ap[2][4];
    #pragma unroll
    for (int s = 0; s < 2; s++)
        #pragma unroll
        for (int p = 0; p < 4; p++) {
            int k = s * 32 + g * 8 + 2 * p;
            w1ap[s][p] = pkrtz(w1[2 * k], w1[2 * k + 2]);
        }
    // layer-3 weights + b2-as-C vectors for this lane's c2 set: c2 = m*16+g*4+r
    float w3r[4][4];
    f32x4 b2v[4];
    #pragma unroll
    for (int m = 0; m < 4; m++)
        #pragma unroll
        for (int r = 0; r < 4; r++) {
            int c2 = m * 16 + g * 4 + r;
            w3r[m][r] = w3[c2];
            b2v[m][r] = b2[c2];
        }
    uint zero16 = 0;
    __syncthreads();

    for (int ii = 0; ii < 4; ii++) {
        int ixl = wid * 4 + ii;
        int iG = iy * 32 + xh * 16 + ixl;
        float outv = 0.f;
        #pragma unroll
        for (int ntH = 0; ntH < 2; ntH++) {
            half8 bf[2][2];
            #pragma unroll
            for (int ntl = 0; ntl < 2; ntl++) {
                int nt = ntH * 2 + ntl;
                uint u0v = u0p[ixl * 64 + nt * 16 + lr];
                const uint* q1p = &Q1p[(nt * 16 + lr) * 36];
                #pragma unroll
                for (int s = 0; s < 2; s++) {
                    uint4 q4 = *(const uint4*)&q1p[s * 16 + g * 4];
                    uint4 hb;
                    hb.x = pk_max_f16(pk_fma_f16(w1ap[s][0], u0v, q4.x), zero16);
                    hb.y = pk_max_f16(pk_fma_f16(w1ap[s][1], u0v, q4.y), zero16);
                    hb.z = pk_max_f16(pk_fma_f16(w1ap[s][2], u0v, q4.z), zero16);
                    hb.w = pk_max_f16(pk_fma_f16(w1ap[s][3], u0v, q4.w), zero16);
                    bf[ntl][s] = __builtin_bit_cast(half8, hb);
                }
            }
            f32x4 acc[4][2];
            #pragma unroll
            for (int m = 0; m < 4; m++)
                #pragma unroll
                for (int l = 0; l < 2; l++)
                    acc[m][l] = __builtin_amdgcn_mfma_f32_16x16x32_f16(
                        w2f[m][0], bf[l][0], b2v[m], 0, 0, 0);
            #pragma unroll
            for (int m = 0; m < 4; m++)
                #pragma unroll
                for (int l = 0; l < 2; l++)
                    acc[m][l] = __builtin_amdgcn_mfma_f32_16x16x32_f16(
                        w2f[m][1], bf[l][1], acc[m][l], 0, 0, 0);
            float t0 = 0.f, t1 = 0.f;
            #pragma unroll
            for (int m = 0; m < 4; m++)
                #pragma unroll
                for (int r = 0; r < 4; r++) {
                    t0 += w3r[m][r] * fmaxf(acc[m][0][r], 0.f);
                    t1 += w3r[m][r] * fmaxf(acc[m][1][r], 0.f);
                }
            t0 += __shfl_xor(t0, 16); t0 += __shfl_xor(t0, 32);
            t1 += __shfl_xor(t1, 16); t1 += __shfl_xor(t1, 32);
            if ((g >> 1) == ntH) outv = (g & 1) ? t1 : t0;
        }
        bias[((size_t)n * 1024 + iG) * 64 + lane] = outv + b3v;
    }
}

// --------- fused attention via MFMA; emits bf16 attb[(b,hw)][ci] ----------
__global__ __launch_bounds__(256) void k_attn(const short* __restrict__ qbt,
                                              const short* __restrict__ kob,
                                              const short* __restrict__ vob,
                                              const float* __restrict__ bias,
                                              short* __restrict__ attb) {
    __shared__ float scr[4][1088];   // per-wave: P [16][68] then outT [64][17]
    int it = blockIdx.x, h = blockIdx.y, b = blockIdx.z;
    int n = b * 4 + h;
    int tid = threadIdx.x, wid = tid >> 6, lane = tid & 63, lr = lane & 15, g = lane >> 4;
    int i0w = it * 64 + wid * 16;
    float* P = scr[wid];

    const short* kb = kob + n * 4096;
    short8b kf[4][2];
    #pragma unroll
    for (int nt = 0; nt < 4; nt++)
        #pragma unroll
        for (int s = 0; s < 2; s++)
            kf[nt][s] = *(const short8b*)&kb[(nt * 16 + lr) * 64 + s * 32 + g * 8];
    const short* vb = vob + n * 4096;
    short8b vf[4][2];
    #pragma unroll
    for (int nt = 0; nt < 4; nt++)
        #pragma unroll
        for (int s = 0; s < 2; s++)
            vf[nt][s] = *(const short8b*)&vb[(nt * 16 + lr) * 64 + s * 32 + g * 8];
    const short* qb = qbt + ((size_t)n * 1024 + i0w + lr) * 64;
    short8b qf[2];
    qf[0] = *(const short8b*)&qb[g * 8];
    qf[1] = *(const short8b*)&qb[32 + g * 8];
    float bv[4][4];
    #pragma unroll
    for (int r = 0; r < 4; r++)
        #pragma unroll
        for (int nt = 0; nt < 4; nt++)
            bv[r][nt] = bias[((size_t)n * 1024 + i0w + g * 4 + r) * 64 + nt * 16 + lr];

    f32x4 acc[4];
    #pragma unroll
    for (int nt = 0; nt < 4; nt++) acc[nt] = (f32x4){0.f, 0.f, 0.f, 0.f};
    #pragma unroll
    for (int s = 0; s < 2; s++)
        #pragma unroll
        for (int nt = 0; nt < 4; nt++)
            acc[nt] = __builtin_amdgcn_mfma_f32_16x16x32_bf16(qf[s], kf[nt][s], acc[nt], 0, 0, 0);

    #pragma unroll
    for (int r = 0; r < 4; r++) {
        float s0 = acc[0][r] + bv[r][0], s1 = acc[1][r] + bv[r][1];
        float s2 = acc[2][r] + bv[r][2], s3 = acc[3][r] + bv[r][3];
        float m = fmaxf(fmaxf(s0, s1), fmaxf(s2, s3));
        m = fmaxf(m, __shfl_xor(m, 1));
        m = fmaxf(m, __shfl_xor(m, 2));
        m = fmaxf(m, __shfl_xor(m, 4));
        m = fmaxf(m, __shfl_xor(m, 8));
        float e0 = __expf(s0 - m), e1 = __expf(s1 - m);
        float e2 = __expf(s2 - m), e3 = __expf(s3 - m);
        float sum = (e0 + e1) + (e2 + e3);
        sum += __shfl_xor(sum, 1);
        sum += __shfl_xor(sum, 2);
        sum += __shfl_xor(sum, 4);
        sum += __shfl_xor(sum, 8);
        float inv = 1.f / sum;
        int row = g * 4 + r;
        P[row * 68 + lr]      = e0 * inv;
        P[row * 68 + 16 + lr] = e1 * inv;
        P[row * 68 + 32 + lr] = e2 * inv;
        P[row * 68 + 48 + lr] = e3 * inv;
    }

    const float* pr = &P[lr * 68];
    float4 a0 = *(float4*)&pr[g * 8];
    float4 a1 = *(float4*)&pr[g * 8 + 4];
    float4 a2 = *(float4*)&pr[32 + g * 8];
    float4 a3 = *(float4*)&pr[32 + g * 8 + 4];
    uint4 up0 = {pack2(a0.x, a0.y), pack2(a0.z, a0.w), pack2(a1.x, a1.y), pack2(a1.z, a1.w)};
    uint4 up1 = {pack2(a2.x, a2.y), pack2(a2.z, a2.w), pack2(a3.x, a3.y), pack2(a3.z, a3.w)};
    short8b pf0 = __builtin_bit_cast(short8b, up0);
    short8b pf1 = __builtin_bit_cast(short8b, up1);

    f32x4 oacc[4];
    #pragma unroll
    for (int nt = 0; nt < 4; nt++) oacc[nt] = (f32x4){0.f, 0.f, 0.f, 0.f};
    #pragma unroll
    for (int nt = 0; nt < 4; nt++) {
        oacc[nt] = __builtin_amdgcn_mfma_f32_16x16x32_bf16(pf0, vf[nt][0], oacc[nt], 0, 0, 0);
        oacc[nt] = __builtin_amdgcn_mfma_f32_16x16x32_bf16(pf1, vf[nt][1], oacc[nt], 0, 0, 0);
    }

    // transpose to [i][d] bf16 via per-wave scratch [d][17]
    #pragma unroll
    for (int nt = 0; nt < 4; nt++)
        #pragma unroll
        for (int r = 0; r < 4; r++)
            P[(nt * 16 + lr) * 17 + g * 4 + r] = oacc[nt][r];
    int il = lane >> 2, dq = lane & 3;
    uint ub[8];
    #pragma unroll
    for (int t = 0; t < 8; t++) {
        float lo = P[(dq * 16 + 2 * t) * 17 + il];
        float hi = P[(dq * 16 + 2 * t + 1) * 17 + il];
        ub[t] = pack2(lo, hi);
    }
    short* op = attb + ((size_t)(b * 1024 + i0w + il)) * 256 + h * 64 + dq * 16;
    uint4 s0v = {ub[0], ub[1], ub[2], ub[3]};
    uint4 s1v = {ub[4], ub[5], ub[6], ub[7]};
    ((uint4*)op)[0] = s0v;
    ((uint4*)op)[1] = s1v;
}

// ------------- output projection via MFMA: C[(b,hw)][co], K=256 -----------
__global__ __launch_bounds__(256) void k_outproj(const short* __restrict__ attb,
                                                 const short* __restrict__ wob,
                                                 const float* __restrict__ bout,
                                                 float* __restrict__ y) {
    int rt = blockIdx.x;             // 256: b = rt>>5, hw-tile of 32
    int ct = blockIdx.y;             // 2
    int tid = threadIdx.x, wid = tid >> 6, lane = tid & 63, lr = lane & 15, g = lane >> 4;
    int wr = wid >> 1, wc = wid & 1;
    int b = rt >> 5;
    int hw0 = (rt & 31) * 32 + wr * 16;
    int cobase = ct * 128 + wc * 64;
    const short* arow = attb + ((size_t)(b * 1024) + hw0) * 256;
    const short* brow = wob + (size_t)cobase * 256;

    f32x4 acc[4];
    #pragma unroll
    for (int nn = 0; nn < 4; nn++) acc[nn] = (f32x4){0.f, 0.f, 0.f, 0.f};
    #pragma unroll
    for (int s = 0; s < 8; s++) {
        short8b af = *(const short8b*)&arow[lr * 256 + s * 32 + g * 8];
        #pragma unroll
        for (int nn = 0; nn < 4; nn++) {
            short8b bf = *(const short8b*)&brow[(nn * 16 + lr) * 256 + s * 32 + g * 8];
            acc[nn] = __builtin_amdgcn_mfma_f32_16x16x32_bf16(af, bf, acc[nn], 0, 0, 0);
        }
    }
    #pragma unroll
    for (int nn = 0; nn < 4; nn++) {
        int co = cobase + nn * 16 + lr;
        float bo = bout[co];
        float4 o = {acc[nn][0] + bo, acc[nn][1] + bo, acc[nn][2] + bo, acc[nn][3] + bo};
        *(float4*)&y[(size_t)b * 262144 + (size_t)co * 1024 + hw0 + g * 4] = o;
    }
}

extern "C" void kernel_launch(void* const* d_in, const int* in_sizes, int n_in,
                              void* d_out, int out_size, void* d_ws, size_t ws_size,
                              hipStream_t stream) {
    const float* x    = (const float*)d_in[0];
    const float* wq   = (const float*)d_in[1];
    const float* wk   = (const float*)d_in[2];
    const float* wv   = (const float*)d_in[3];
    const float* wdw  = (const float*)d_in[4];
    const float* bdw  = (const float*)d_in[5];
    const float* wpw  = (const float*)d_in[6];
    const float* cw1  = (const float*)d_in[7];
    const float* cb1  = (const float*)d_in[8];
    const float* cw2  = (const float*)d_in[9];
    const float* cb2  = (const float*)d_in[10];
    const float* cw3  = (const float*)d_in[11];
    const float* cb3  = (const float*)d_in[12];
    const float* wout = (const float*)d_in[13];
    const float* bout = (const float*)d_in[14];
    float* y  = (float*)d_out;
    float* ws = (float*)d_ws;

    float* q    = ws;                          // 8MB f32 (dead after k_dw)
    short* attb = (short*)ws;                  // alias: bf16 attn out [b*hw][ci]
    float* bias = ws + 2097152;
    float* kv   = ws + 4194304;
    float* vgs  = ws + 4325376;
    short* qbt  = (short*)(ws + 4329472);
    short* kob  = (short*)(ws + 5378048);
    short* vob  = (short*)(ws + 5443584);
    float* gdw  = ws + 5509120;
    short* wob  = (short*)(ws + 5640192);      // 65536 bf16
    uint*  u0g  = (uint*)(ws + 5672960);       // 65536 uint (f16x2 u0 table)

    k_qproj  <<<dim3(8, 4, 8),  256, 0, stream>>>(x, wq, q, qbt);
    k_wcvt   <<<32,             256, 0, stream>>>(wout, wob);
    k_dw     <<<dim3(8, 32),    256, 0, stream>>>(q, wdw, bdw, gdw);
    k_pw     <<<32,              64, 0, stream>>>(gdw, wpw, vgs);
    k_u0     <<<32,             256, 0, stream>>>(vgs, u0g);
    k_sample <<<512,            256, 0, stream>>>(x, vgs, kv);
    k_kvproj <<<32,             256, 0, stream>>>(kv, wk, wv, kob, vob);
    k_cpb    <<<dim3(64, 32),   256, 0, stream>>>(vgs, u0g, cw1, cb1, cw2, cb2, cw3, cb3, bias);
    k_attn   <<<dim3(16, 4, 8), 256, 0, stream>>>(qbt, kob, vob, bias, attb);
    k_outproj<<<dim3(256, 2),   256, 0, stream>>>(attb, wob, bout, y);
}